// Round 10
// baseline (442.160 us; speedup 1.0000x reference)
//
#include <hip/hip_runtime.h>

#define Bsz 4096
#define Tt  256
#define Ff  32
#define H1  64
#define H2  32
#define NTAPS 3
#define BT  16      // 256 blocks -> 1 block/CU (LDS-forced), full 16-row A-frags
#define NTHR 1024   // 16 waves: 0-7 heavy (2 L1 gate-tiles), 8-15 light (1 L2 tile + DMA)
#define CH  16      // x-staging chunk (timesteps)
#define HDS 33
#define GTS 260     // f32 stride per gate tile (16x16 + 4 pad -> bank drift)

typedef _Float16 half8  __attribute__((ext_vector_type(8)));
typedef __fp16   fp16x2 __attribute__((ext_vector_type(2)));   // cvt_pkrtz return type
typedef float    f32x4  __attribute__((ext_vector_type(4)));

// fused LSTM unit: 5 exp + 2 rcp (hardware trans — r9 proved poly-exp2 is WORSE:
// trans issues ~like VALU; total instruction count is what matters)
__device__ __forceinline__ float lstm_unit(float pi, float pf, float pg, float po,
                                           float& c) {
    const float K1 = 1.4426950408889634f;   // log2(e)
    float ei = __builtin_amdgcn_exp2f(-K1 * pi);
    float ef = __builtin_amdgcn_exp2f(-K1 * pf);
    float eg = __builtin_amdgcn_exp2f(-2.0f * K1 * __builtin_fabsf(pg));
    float eo = __builtin_amdgcn_exp2f(-K1 * po);
    float p1 = (1.0f + ei) * (1.0f + eg);
    float pf1 = 1.0f + ef;
    float R  = __builtin_amdgcn_rcpf(p1 * pf1);          // 1/((1+ei)(1+eg)(1+ef))
    float t1 = c * p1;                                    // c*(1+ei)(1+eg)
    float t2 = __builtin_copysignf(1.0f - eg, pg) * pf1;  // tanh(g)num*sig(i)num*(1+ef)
    c = (t1 + t2) * R;                                    // f*c + i*g
    float ec = __builtin_amdgcn_exp2f(-2.0f * K1 * __builtin_fabsf(c));
    float th = (1.0f - ec) * __builtin_amdgcn_rcpf((1.0f + eo) * (1.0f + ec));
    return __builtin_copysignf(th, c);                    // o*tanh(c)
}

#define MFMA16(a, b, c) __builtin_amdgcn_mfma_f32_16x16x32_f16((a), (b), (c), 0, 0, 0)

// async global->LDS DMA, 16B per lane; LDS dst = uniform base + lane*16
__device__ __forceinline__ void dma16(const float* gp, const float* lp) {
    __builtin_amdgcn_global_load_lds(
        (const __attribute__((address_space(1))) void*)gp,
        (__attribute__((address_space(3))) void*)lp, 16, 0, 0);
}

__device__ __forceinline__ half8 cvt8(f32x4 lo, f32x4 hi) {
    union { half8 v; fp16x2 h[4]; } ax;
    ax.h[0] = __builtin_amdgcn_cvt_pkrtz(lo[0], lo[1]);
    ax.h[1] = __builtin_amdgcn_cvt_pkrtz(lo[2], lo[3]);
    ax.h[2] = __builtin_amdgcn_cvt_pkrtz(hi[0], hi[1]);
    ax.h[3] = __builtin_amdgcn_cvt_pkrtz(hi[2], hi[3]);
    return ax.v;
}

// 1024-thread block: 16 waves = 4 waves/SIMD forced resident -> VGPR cap 128.
__global__ __launch_bounds__(NTHR, 1)
void lstm2_fused(const float* __restrict__ x,
                 const float* __restrict__ Wih1, const float* __restrict__ Whh1,
                 const float* __restrict__ bih1, const float* __restrict__ bhh1,
                 const float* __restrict__ Wih2, const float* __restrict__ Whh2,
                 const float* __restrict__ bih2, const float* __restrict__ bhh2,
                 const float* __restrict__ Whead, const float* __restrict__ bhead,
                 float* __restrict__ out)
{
    // h buffers: [buf][k-block][batch][8 halves] — A-frag read is 64 consecutive
    // 16B slots (conflict-free b128 sweep)
    __shared__ __align__(16) _Float16 sH1f[2][8][BT][8];    // 4 KB
    __shared__ __align__(16) _Float16 sH2f[2][4][BT][8];    // 2 KB
    // x chunk: [buf][t][f4][b][4] f32 — f4-major so DMA lane*16B is contiguous
    __shared__ __align__(16) float    sXC[2][CH][8][BT][4]; // 64 KB
    // gate pre-activations: 24 tiles (16 L1 + 8 L2) x [col][row] f32, padded stride
    __shared__ __align__(16) float    sG[24 * GTS];         // ~25 KB
    __shared__ __align__(16) float    sHead[BT][HDS];       // ~2 KB
    // total ~97 KB -> exactly 1 block/CU

    const int tid  = threadIdx.x;
    const int wid  = tid >> 6;        // 0..15
    const int lane = tid & 63;
    const int l15  = lane & 15;
    const int q    = lane >> 4;       // 0..3
    const int b0   = blockIdx.x * BT;
    const bool heavy = (wid < 8);

    // ---- phase2 unit mapping (constant per lane) ----
    // heavy lane: units (b=l15, h0=wid*4+q) and (b, h0+32); light: (b=l15, h2u)
    const int h0   = (wid & 7) * 4 + q;                // 0..31
    const int cpH  = ((wid & 3) * 4 + q) * 16 + l15;   // (h&15)*16 + b  (f32 idx)
    const int u0   = (wid & 7) >> 2;                   // heavy: u of unit j=0
    const int w8   = (wid - 8) & 7;
    const int h2u  = w8 * 4 + q;                       // light h2 0..31
    const int cpL  = ((w8 & 3) * 4 + q) * 16 + l15;
    const int u2g  = w8 >> 2;
    // h-write offsets (halves)
    const int offH0 = (h0 >> 3) * 128 + l15 * 8 + (h0 & 7);       // j=0; j=1 adds 512
    const int offL  = (h2u >> 3) * 128 + l15 * 8 + (h2u & 7);

    // ---- prologue: light waves stage chunk 0 (t = 0..15) ----
    if (!heavy) {
        #pragma unroll
        for (int jj = 0; jj < 2; ++jj)
            #pragma unroll
            for (int h = 0; h < 2; ++h) {
                int t = (wid - 8) * 2 + jj;
                const float* src = x + (size_t)(b0 + l15) * Tt * Ff + t * Ff + (h * 4 + q) * 4;
                dma16(src, &sXC[0][t][h * 4][0][0]);
            }
    }

    // ---- weight fragments (one time) ----
    // heavy: wF[T][0,1] = Whh1 K-halves, wF[T][2] = Wih1 (tile tl = 2*wid+T, G=tl>>2,u=tl&3)
    // light: wF[0][0] = Whh2, wF[0][1,2] = Wih2 (tile tl2 = wid-8, G=tl2>>1,u2=tl2&1)
    half8 wF[2][3];
    float biasF[2];
    if (heavy) {
        #pragma unroll
        for (int T = 0; T < 2; ++T) {
            int tl = 2 * wid + T;
            int G = tl >> 2, u = tl & 3;
            int gr = G * 64 + u * 16 + l15;
            half8 v0, v1, vx;
            #pragma unroll
            for (int e = 0; e < 8; ++e) {
                v0[e] = (_Float16)Whh1[gr * H1 + q * 8 + e];
                v1[e] = (_Float16)Whh1[gr * H1 + 32 + q * 8 + e];
                vx[e] = (_Float16)Wih1[gr * Ff + q * 8 + e];
            }
            wF[T][0] = v0; wF[T][1] = v1; wF[T][2] = vx;
            biasF[T] = bih1[gr] + bhh1[gr];
        }
    } else {
        int tl2 = wid - 8;
        int G = tl2 >> 1, u2 = tl2 & 1;
        int gr2 = G * 32 + u2 * 16 + l15;
        half8 v0, v1, v2;
        #pragma unroll
        for (int e = 0; e < 8; ++e) {
            v0[e] = (_Float16)Whh2[gr2 * H2 + q * 8 + e];
            v1[e] = (_Float16)Wih2[gr2 * H1 + q * 8 + e];
            v2[e] = (_Float16)Wih2[gr2 * H1 + 32 + q * 8 + e];
        }
        wF[0][0] = v0; wF[0][1] = v1; wF[0][2] = v2;
        biasF[0] = bih2[gr2] + bhh2[gr2];
        biasF[1] = 0.0f;
    }

    // ---- zero h(-1) buffers ----
    for (int idx = tid; idx < 2 * 8 * BT * 8; idx += NTHR) ((_Float16*)sH1f)[idx] = (_Float16)0.0f;
    for (int idx = tid; idx < 2 * 4 * BT * 8; idx += NTHR) ((_Float16*)sH2f)[idx] = (_Float16)0.0f;

    __syncthreads();   // drains chunk-0 DMA + init writes

    float cs0 = 0.0f, cs1 = 0.0f;

    #pragma unroll 2
    for (int i = 0; i <= Tt; ++i) {
        const int cur = i & 1, nxt = cur ^ 1;
        const int cb  = (i >> 4) & 1;

        // ---- chunk-boundary DMA (light), at step top ----
        if (!heavy && (i & 15) == 0 && i + CH < Tt) {
            #pragma unroll
            for (int jj = 0; jj < 2; ++jj)
                #pragma unroll
                for (int h = 0; h < 2; ++h) {
                    int t = i + CH + (wid - 8) * 2 + jj;
                    const float* src = x + (size_t)(b0 + l15) * Tt * Ff + (size_t)t * Ff + (h * 4 + q) * 4;
                    dma16(src, &sXC[cb ^ 1][t & 15][h * 4][0][0]);
                }
        }

        // h1(i-1) fragments (heavy A; light K-part A)
        half8 a0 = *(const half8*)&sH1f[nxt][q][l15][0];
        half8 a1 = *(const half8*)&sH1f[nxt][4 + q][l15][0];

        // ---- phase 1: MFMA gate tiles -> sG ----
        if (heavy) {
            if (i < Tt) {
                f32x4 lo = *(const f32x4*)&sXC[cb][i & 15][2 * q][l15][0];
                f32x4 hi = *(const f32x4*)&sXC[cb][i & 15][2 * q + 1][l15][0];
                half8 ax = cvt8(lo, hi);
                #pragma unroll
                for (int T = 0; T < 2; ++T) {
                    f32x4 a = {biasF[T], biasF[T], biasF[T], biasF[T]};
                    a = MFMA16(a0, wF[T][0], a);
                    a = MFMA16(a1, wF[T][1], a);
                    a = MFMA16(ax, wF[T][2], a);
                    *(f32x4*)&sG[(2 * wid + T) * GTS + l15 * 16 + q * 4] = a;
                }
            }
        } else if (i >= 1) {
            half8 ah = *(const half8*)&sH2f[nxt][q][l15][0];
            f32x4 a = {biasF[0], biasF[0], biasF[0], biasF[0]};
            a = MFMA16(ah, wF[0][0], a);
            a = MFMA16(a0, wF[0][1], a);
            a = MFMA16(a1, wF[0][2], a);
            *(f32x4*)&sG[(16 + (wid - 8)) * GTS + l15 * 16 + q * 4] = a;
        }

        __syncthreads();   // barrier 1: gates visible

        // ---- phase 2: lstm on gates, write h ----
        if (heavy) {
            if (i < Tt) {
                #pragma unroll
                for (int j = 0; j < 2; ++j) {
                    int base = (u0 + 2 * j) * GTS + cpH;        // tile (G=0, u0+2j)
                    float pi = sG[base];
                    float pf = sG[base + 4 * GTS];
                    float pg = sG[base + 8 * GTS];
                    float po = sG[base + 12 * GTS];
                    float hv = lstm_unit(pi, pf, pg, po, j ? cs1 : cs0);
                    ((_Float16*)sH1f)[cur * 1024 + offH0 + j * 512] = (_Float16)hv;
                }
            }
        } else if (i >= 1) {
            int base = (16 + u2g) * GTS + cpL;
            float pi = sG[base];
            float pf = sG[base + 2 * GTS];
            float pg = sG[base + 4 * GTS];
            float po = sG[base + 6 * GTS];
            float hv = lstm_unit(pi, pf, pg, po, cs0);
            if (i == Tt) sHead[l15][h2u] = hv;
            else ((_Float16*)sH2f)[cur * 512 + offL] = (_Float16)hv;
        }

        __syncthreads();   // barrier 2: h visible for next step, sG reusable
    }

    // ---- head ----
    if (tid < BT * NTAPS) {
        int b = tid / NTAPS, n = tid - b * NTAPS;
        float s = bhead[n];
        #pragma unroll
        for (int k = 0; k < H2; ++k) s = fmaf(sHead[b][k], Whead[n * H2 + k], s);
        out[(size_t)(b0 + b) * NTAPS + n] = s;
    }
}

extern "C" void kernel_launch(void* const* d_in, const int* in_sizes, int n_in,
                              void* d_out, int out_size, void* d_ws, size_t ws_size,
                              hipStream_t stream) {
    const float* xp    = (const float*)d_in[0];
    const float* Wih1  = (const float*)d_in[1];
    const float* Whh1  = (const float*)d_in[2];
    const float* bih1  = (const float*)d_in[3];
    const float* bhh1  = (const float*)d_in[4];
    const float* Wih2  = (const float*)d_in[5];
    const float* Whh2  = (const float*)d_in[6];
    const float* bih2  = (const float*)d_in[7];
    const float* bhh2  = (const float*)d_in[8];
    const float* Whead = (const float*)d_in[9];
    const float* bhead = (const float*)d_in[10];
    float* outp = (float*)d_out;

    hipLaunchKernelGGL(lstm2_fused, dim3(Bsz / BT), dim3(NTHR), 0, stream,
                       xp, Wih1, Whh1, bih1, bhh1, Wih2, Whh2, bih2, bhh2,
                       Whead, bhead, outp);
}